// Round 4
// baseline (2961.584 us; speedup 1.0000x reference)
//
#include <hip/hip_runtime.h>
#include <stdint.h>

typedef __attribute__((ext_vector_type(8))) short s16x8;
typedef __attribute__((ext_vector_type(8))) unsigned short u16x8;
typedef __attribute__((ext_vector_type(4))) unsigned short u16x4;
typedef __attribute__((ext_vector_type(4))) float f32x4;

__device__ inline unsigned short f2b(float f){
  unsigned u = __builtin_bit_cast(unsigned, f);
  u = u + 0x7fffu + ((u >> 16) & 1u);
  return (unsigned short)(u >> 16);
}
__device__ inline float b2f(unsigned short h){
  unsigned u = ((unsigned)h) << 16;
  return __builtin_bit_cast(float, u);
}

typedef __attribute__((address_space(1))) const unsigned g_uint;
typedef __attribute__((address_space(3))) unsigned l_uint;

__device__ inline void gload_lds16(const void* g, void* l){
  __builtin_amdgcn_global_load_lds((g_uint*)reinterpret_cast<uintptr_t>(g),
                                   (l_uint*)reinterpret_cast<uintptr_t>(l), 16, 0, 0);
}

// C[m][n] = sum_k A[m][k] * B[n][k]   (A: [M,K], B: [N,K], both row-major bf16)
// K range per block: [bz*KS, bz*KS+KS);  leading dim = gridDim.z * KS
// EPI 2: Cb[idx] = bf16(v + bias[row])
// EPI 4: Cf[bz*M*N + idx] = v                    (split-K partial)
// EPI 5: e = exp(v*scale); Cb[idx] = bf16(e); part[(bx*2+wc)*M+row] = rowsum(e)
// EPI 6: EPI 5 + Cf[idx] = v*scale               (last-iter z output)
template<int EPI>
__global__ __launch_bounds__(256, 2) void gemm_bt(
    const unsigned short* __restrict__ A, const unsigned short* __restrict__ B,
    int M, int N, int KS, float scale, const float* __restrict__ bias,
    float* __restrict__ Cf, unsigned short* __restrict__ Cb,
    float* __restrict__ part)
{
  __shared__ unsigned short As[128*64];
  __shared__ unsigned short Bs[128*64];
  const int tid  = threadIdx.x;
  const int wid  = tid >> 6, lane = tid & 63;
  const int wr   = wid >> 1, wc = wid & 1;

  // ---- bijective XCD-aware swizzle (all launch grids have total % 8 == 0) ----
  const unsigned gx = gridDim.x, gy = gridDim.y;
  const unsigned lin = blockIdx.x + gx*(blockIdx.y + gy*blockIdx.z);
  const unsigned q   = (gx*gy*gridDim.z) >> 3;
  const unsigned w   = (lin & 7)*q + (lin >> 3);
  const unsigned bxs = w % gx;
  const unsigned rest = w / gx;
  const unsigned bys = rest % gy;
  const unsigned bzs = rest / gy;

  const int bm   = bys * 128, bn = bxs * 128;
  const int kb   = bzs * KS, ke = kb + KS;

  f32x4 acc[4][4] = {};

  // ---- staging geometry (global source pre-swizzled; LDS written linearly) ----
  const int l8   = lane >> 3;
  const int scol = ((((lane & 7) << 4) ^ (l8 << 4)) >> 1);
  const int Klead = gridDim.z * KS;

  const unsigned short* Ag[4]; const unsigned short* Bg[4];
  unsigned short* Al[4]; unsigned short* Bl[4];
  #pragma unroll
  for (int i = 0; i < 4; ++i){
    const int row = wid*32 + i*8 + l8;
    Ag[i] = A + (size_t)(bm + row) * Klead + scol;
    Bg[i] = B + (size_t)(bn + row) * Klead + scol;
    Al[i] = As + (wid*4 + i) * 512;
    Bl[i] = Bs + (wid*4 + i) * 512;
  }

  // ---- fragment read geometry ----
  const int fr    = lane & 15;
  const int fk    = (lane >> 4) << 4;
  const int amask = (fr & 7) << 4;

  for (int k0 = kb; k0 < ke; k0 += 64){
    if (k0 != kb) __syncthreads();
    #pragma unroll
    for (int i = 0; i < 4; ++i){
      gload_lds16(Ag[i] + k0, Al[i]);
      gload_lds16(Bg[i] + k0, Bl[i]);
    }
    __syncthreads();
    #pragma unroll
    for (int kk = 0; kk < 2; ++kk){
      s16x8 af[4], bf[4];
      #pragma unroll
      for (int m = 0; m < 4; ++m){
        const int row = (wr << 6) + m*16 + fr;
        const int off = row*128 + (((kk << 6) + fk) ^ amask);
        af[m] = *(const s16x8*)((const char*)As + off);
      }
      #pragma unroll
      for (int n = 0; n < 4; ++n){
        const int row = (wc << 6) + n*16 + fr;
        const int off = row*128 + (((kk << 6) + fk) ^ amask);
        bf[n] = *(const s16x8*)((const char*)Bs + off);
      }
      #pragma unroll
      for (int m = 0; m < 4; ++m)
        #pragma unroll
        for (int n = 0; n < 4; ++n)
          acc[m][n] = __builtin_amdgcn_mfma_f32_16x16x32_bf16(af[m], bf[n], acc[m][n], 0, 0, 0);
    }
  }

  // ---- epilogue ----
  const int gr0 = bm + (wr << 6) + ((lane >> 4) << 2);
  const int gc0 = bn + (wc << 6) + (lane & 15);
  if (EPI == 5 || EPI == 6){
    // exp epilogue + per-row partial sums (no-max softmax)
    #pragma unroll
    for (int m = 0; m < 4; ++m){
      #pragma unroll
      for (int j = 0; j < 4; ++j){
        const int row = gr0 + m*16 + j;
        float rs = 0.f;
        #pragma unroll
        for (int n = 0; n < 4; ++n){
          const int col = gc0 + n*16;
          const size_t idx = (size_t)row * N + col;
          const float zz = acc[m][n][j] * scale;
          if (EPI == 6) Cf[idx] = zz;
          const unsigned short eb = f2b(__expf(zz));
          Cb[idx] = eb;
          rs += b2f(eb);
        }
        #pragma unroll
        for (int o = 8; o; o >>= 1) rs += __shfl_xor(rs, o, 64);
        if ((lane & 15) == 0) part[((size_t)bxs*2 + wc)*M + row] = rs;
      }
    }
  } else {
    const size_t pbase = (size_t)bzs * M * N;
    #pragma unroll
    for (int m = 0; m < 4; ++m){
      #pragma unroll
      for (int n = 0; n < 4; ++n){
        #pragma unroll
        for (int j = 0; j < 4; ++j){
          const int row = gr0 + m*16 + j;
          const int col = gc0 + n*16;
          const size_t idx = (size_t)row * N + col;
          const float v = acc[m][n][j];
          if      (EPI == 2) Cb[idx] = f2b(v + bias[row]);
          else if (EPI == 4) Cf[pbase + idx] = v;
        }
      }
    }
  }
}

// linv[r] = 1 / sum_p part[p][r]
__global__ __launch_bounds__(256) void rowsum_inv(const float* __restrict__ part,
                                                  int P, int R, float* __restrict__ linv)
{
  const int r = blockIdx.x * 256 + threadIdx.x;
  if (r >= R) return;
  float s = 0.f;
  for (int p = 0; p < P; ++p) s += part[(size_t)p * R + r];
  linv[r] = 1.0f / s;
}

// split-K reduce with row normalization:
// Cf[i] += linv[row]*sum_s P[s][i]; Cb[i] = bf16(Cf[i]); 4 floats/thread
__global__ __launch_bounds__(256) void reduce_splitk(
    const float* __restrict__ P, int S, size_t stride4,
    const float* __restrict__ linv, int d4,
    float* __restrict__ Cf, unsigned short* __restrict__ Cb, int n4)
{
  const int i = blockIdx.x * 256 + threadIdx.x;
  if (i >= n4) return;
  f32x4 s = {0.f, 0.f, 0.f, 0.f};
  for (int k = 0; k < S; ++k) s += ((const f32x4*)P)[(size_t)k * stride4 + i];
  const float li = linv[i / d4];
  f32x4 r = ((const f32x4*)Cf)[i];
  r += s * li;
  ((f32x4*)Cf)[i] = r;
  u16x4 o;
  o[0] = f2b(r[0]); o[1] = f2b(r[1]); o[2] = f2b(r[2]); o[3] = f2b(r[3]);
  ((u16x4*)Cb)[i] = o;
}

// fp32 -> (optional fp32 copy) + bf16, 8 elements/thread
__global__ void cvt8(const float* __restrict__ src, float* __restrict__ dstf,
                     unsigned short* __restrict__ dstb, int n8)
{
  const int i = blockIdx.x * 256 + threadIdx.x;
  if (i >= n8) return;
  const f32x4 a = ((const f32x4*)src)[2*i];
  const f32x4 b = ((const f32x4*)src)[2*i + 1];
  if (dstf){ ((f32x4*)dstf)[2*i] = a; ((f32x4*)dstf)[2*i + 1] = b; }
  u16x8 o;
  o[0]=f2b(a[0]); o[1]=f2b(a[1]); o[2]=f2b(a[2]); o[3]=f2b(a[3]);
  o[4]=f2b(b[0]); o[5]=f2b(b[1]); o[6]=f2b(b[2]); o[7]=f2b(b[3]);
  ((u16x8*)dstb)[i] = o;
}

extern "C" void kernel_launch(void* const* d_in, const int* in_sizes, int n_in,
                              void* d_out, int out_size, void* d_ws, size_t ws_size,
                              hipStream_t stream)
{
  (void)in_sizes; (void)n_in; (void)out_size; (void)ws_size;
  const float* sents = (const float*)d_in[0];
  const float* funcs = (const float*)d_in[1];
  const float* WvA   = (const float*)d_in[2];   // Wv_f2s
  const float* bvA   = (const float*)d_in[3];
  const float* WvB   = (const float*)d_in[4];   // Wv_s2f
  const float* bvB   = (const float*)d_in[5];

  const int NS = 16384, NF = 4096, D = 768;

  float* outS = (float*)d_out;                        // [NS, D]
  float* outF = outS + (size_t)NS * D;                // [NF, D]
  float* outZ = outF + (size_t)NF * D;                // [NS, NF]

  char* ws = (char*)d_ws;
  unsigned short* att = (unsigned short*)ws;  ws += (size_t)NS * NF * 2;   // shared att / z2 buffer
  unsigned short* z2  = att;                                               // disjoint lifetimes
  unsigned short* sb  = (unsigned short*)ws;  ws += (size_t)NS * D * 2;
  unsigned short* fb  = (unsigned short*)ws;  ws += (size_t)NF * D * 2;
  unsigned short* fvT = (unsigned short*)ws;  ws += (size_t)D * NF * 2;
  unsigned short* svT = (unsigned short*)ws;  ws += (size_t)D * NS * 2;
  float* part = (float*)ws;  ws += (size_t)1048576 * 4;   // 4MB row-sum partials (64*16384 == 256*4096)
  float* linv = (float*)ws;  ws += (size_t)NS * 4;        // 64KB inverse row sums
  float* Pbuf = (float*)ws;  ws += (size_t)NS * D * 2 * 4;  // 100.7MB split-K partials

  const float scale = 0.036084391824351615f;  // 1/sqrt(768)

  cvt8<<<dim3((NS*D/8 + 255)/256), 256, 0, stream>>>(sents, outS, sb, NS*D/8);
  cvt8<<<dim3((NF*D/8 + 255)/256), 256, 0, stream>>>(funcs, outF, fb, NF*D/8);
  cvt8<<<dim3((D*D/8 + 255)/256),  256, 0, stream>>>(WvA, nullptr, (unsigned short*)part, D*D/8);
  cvt8<<<dim3((D*D/8 + 255)/256),  256, 0, stream>>>(WvB, nullptr, ((unsigned short*)part) + D*D, D*D/8);
  unsigned short* wA = (unsigned short*)part;          // weights live in part buffer
  unsigned short* wB = wA + D*D;                       // until first EPI5 GEMM of iter 0?  NO —
  // part is overwritten by the z-GEMM each iteration; weights are needed every
  // iteration for fvT/svT.  Give weights their own slice instead:
  unsigned short* wA2 = (unsigned short*)(ws);  ws += (size_t)D * D * 2;
  unsigned short* wB2 = (unsigned short*)(ws);  ws += (size_t)D * D * 2;
  cvt8<<<dim3((D*D/8 + 255)/256),  256, 0, stream>>>(WvA, nullptr, wA2, D*D/8);
  cvt8<<<dim3((D*D/8 + 255)/256),  256, 0, stream>>>(WvB, nullptr, wB2, D*D/8);

  for (int it = 0; it < 4; ++it){
    // fvT[d][f] = sum_k Wv_f2s[d][k]*func_hid[f][k] + bv_f2s[d]   (= func_val^T)
    gemm_bt<2><<<dim3(NF/128, D/128, 1), dim3(256), 0, stream>>>(wA2, fb, D, NF, D, 0.f, bvA, nullptr, fvT, nullptr);
    if (it < 3){
      // att = exp(scale * sents_hid @ func_hid^T)  (bf16, unnormalized) + row partials
      gemm_bt<5><<<dim3(NF/128, NS/128, 1), dim3(256), 0, stream>>>(sb, fb, NS, NF, D, scale, nullptr, nullptr, att, part);
    } else {
      // + z fp32 (returned)
      gemm_bt<6><<<dim3(NF/128, NS/128, 1), dim3(256), 0, stream>>>(sb, fb, NS, NF, D, scale, nullptr, outZ, att, part);
    }
    rowsum_inv<<<dim3(NS/256), 256, 0, stream>>>(part, 64, NS, linv);
    // sents_hid += linv * (att_un @ func_val) : split-K S=2, then normalize-reduce
    gemm_bt<4><<<dim3(D/128, NS/128, 2), dim3(256), 0, stream>>>(att, fvT, NS, D, 2048, 0.f, nullptr, Pbuf, nullptr, nullptr);
    reduce_splitk<<<dim3(NS*D/4/256), 256, 0, stream>>>(Pbuf, 2, (size_t)NS*D/4, linv, D/4, outS, sb, NS*D/4);
    // svT[d][s] = sum_k Wv_s2f[d][k]*sents_hid[s][k] + bv_s2f[d]  (= sent_val^T)
    gemm_bt<2><<<dim3(NS/128, D/128, 1), dim3(256), 0, stream>>>(wB2, sb, D, NS, D, 0.f, bvB, nullptr, svT, nullptr);
    // z2_un = exp(scale * func_hid @ sents_hid^T)  (bf16) + row partials
    gemm_bt<5><<<dim3(NS/128, NF/128, 1), dim3(256), 0, stream>>>(fb, sb, NF, NS, D, scale, nullptr, nullptr, z2, part);
    rowsum_inv<<<dim3(NF/256), 256, 0, stream>>>(part, 256, NF, linv);
    // func_hid += linv * (z2_un @ sent_val) : split-K S=8, then normalize-reduce
    gemm_bt<4><<<dim3(D/128, NF/128, 8), dim3(256), 0, stream>>>(z2, svT, NF, D, 2048, 0.f, nullptr, Pbuf, nullptr, nullptr);
    reduce_splitk<<<dim3(NF*D/4/256), 256, 0, stream>>>(Pbuf, 8, (size_t)NF*D/4, linv, D/4, outF, fb, NF*D/4);
  }
}

// Round 6
// 2580.391 us; speedup vs baseline: 1.1477x; 1.1477x over previous
//
#include <hip/hip_runtime.h>
#include <stdint.h>

typedef __attribute__((ext_vector_type(8))) short s16x8;
typedef __attribute__((ext_vector_type(8))) unsigned short u16x8;
typedef __attribute__((ext_vector_type(4))) unsigned short u16x4;
typedef __attribute__((ext_vector_type(4))) float f32x4;

__device__ inline unsigned short f2b(float f){
  unsigned u = __builtin_bit_cast(unsigned, f);
  u = u + 0x7fffu + ((u >> 16) & 1u);
  return (unsigned short)(u >> 16);
}
__device__ inline float b2f(unsigned short h){
  unsigned u = ((unsigned)h) << 16;
  return __builtin_bit_cast(float, u);
}

typedef __attribute__((address_space(1))) const unsigned g_uint;
typedef __attribute__((address_space(3))) unsigned l_uint;

__device__ inline void gload_lds16(const void* g, void* l){
  __builtin_amdgcn_global_load_lds((g_uint*)reinterpret_cast<uintptr_t>(g),
                                   (l_uint*)reinterpret_cast<uintptr_t>(l), 16, 0, 0);
}

// C[m][n] = sum_k A[m][k] * B[n][k]   (A: [M,K], B: [N,K], both row-major bf16)
// K range per block: [bz*KS, bz*KS+KS);  leading dim = gridDim.z * KS
// EPI 2: Cb[idx] = bf16(v + bias[row])
// EPI 4: Cf[bz*M*N + idx] = v                    (split-K partial)
// EPI 5: Cb[idx] = bf16(exp(v*scale))            (unnormalized softmax numerator)
// EPI 6: EPI 5 + Cf[idx] = v*scale               (last-iter z output)
template<int EPI>
__global__ __launch_bounds__(256, 2) void gemm_bt(
    const unsigned short* __restrict__ A, const unsigned short* __restrict__ B,
    int M, int N, int KS, float scale, const float* __restrict__ bias,
    float* __restrict__ Cf, unsigned short* __restrict__ Cb)
{
  __shared__ unsigned short As[128*64];
  __shared__ unsigned short Bs[128*64];
  const int tid  = threadIdx.x;
  const int wid  = tid >> 6, lane = tid & 63;
  const int wr   = wid >> 1, wc = wid & 1;

  // ---- bijective XCD-aware swizzle (all launch grids have total % 8 == 0) ----
  const unsigned gx = gridDim.x, gy = gridDim.y;
  const unsigned lin = blockIdx.x + gx*(blockIdx.y + gy*blockIdx.z);
  const unsigned q   = (gx*gy*gridDim.z) >> 3;
  const unsigned w   = (lin & 7)*q + (lin >> 3);
  const unsigned bxs = w % gx;
  const unsigned rest = w / gx;
  const unsigned bys = rest % gy;
  const unsigned bzs = rest / gy;

  const int bm   = bys * 128, bn = bxs * 128;
  const int kb   = bzs * KS, ke = kb + KS;

  f32x4 acc[4][4] = {};

  // ---- staging geometry (global source pre-swizzled; LDS written linearly) ----
  const int l8   = lane >> 3;
  const int scol = ((((lane & 7) << 4) ^ (l8 << 4)) >> 1);
  const int Klead = gridDim.z * KS;

  const unsigned short* Ag[4]; const unsigned short* Bg[4];
  unsigned short* Al[4]; unsigned short* Bl[4];
  #pragma unroll
  for (int i = 0; i < 4; ++i){
    const int row = wid*32 + i*8 + l8;
    Ag[i] = A + (size_t)(bm + row) * Klead + scol;
    Bg[i] = B + (size_t)(bn + row) * Klead + scol;
    Al[i] = As + (wid*4 + i) * 512;
    Bl[i] = Bs + (wid*4 + i) * 512;
  }

  // ---- fragment read geometry ----
  const int fr    = lane & 15;
  const int fk    = (lane >> 4) << 4;
  const int amask = (fr & 7) << 4;

  for (int k0 = kb; k0 < ke; k0 += 64){
    if (k0 != kb) __syncthreads();
    #pragma unroll
    for (int i = 0; i < 4; ++i){
      gload_lds16(Ag[i] + k0, Al[i]);
      gload_lds16(Bg[i] + k0, Bl[i]);
    }
    __syncthreads();
    #pragma unroll
    for (int kk = 0; kk < 2; ++kk){
      s16x8 af[4], bf[4];
      #pragma unroll
      for (int m = 0; m < 4; ++m){
        const int row = (wr << 6) + m*16 + fr;
        const int off = row*128 + (((kk << 6) + fk) ^ amask);
        af[m] = *(const s16x8*)((const char*)As + off);
      }
      #pragma unroll
      for (int n = 0; n < 4; ++n){
        const int row = (wc << 6) + n*16 + fr;
        const int off = row*128 + (((kk << 6) + fk) ^ amask);
        bf[n] = *(const s16x8*)((const char*)Bs + off);
      }
      #pragma unroll
      for (int m = 0; m < 4; ++m)
        #pragma unroll
        for (int n = 0; n < 4; ++n)
          acc[m][n] = __builtin_amdgcn_mfma_f32_16x16x32_bf16(af[m], bf[n], acc[m][n], 0, 0, 0);
    }
  }

  // ---- epilogue ----
  const int gr0 = bm + (wr << 6) + ((lane >> 4) << 2);
  const int gc0 = bn + (wc << 6) + (lane & 15);
  const size_t pbase = (size_t)bzs * M * N;
  #pragma unroll
  for (int m = 0; m < 4; ++m){
    #pragma unroll
    for (int n = 0; n < 4; ++n){
      #pragma unroll
      for (int j = 0; j < 4; ++j){
        const int row = gr0 + m*16 + j;
        const int col = gc0 + n*16;
        const size_t idx = (size_t)row * N + col;
        const float v = acc[m][n][j];
        if      (EPI == 2) Cb[idx] = f2b(v + bias[row]);
        else if (EPI == 4) Cf[pbase + idx] = v;
        else if (EPI == 5) Cb[idx] = f2b(__expf(v * scale));
        else if (EPI == 6){ const float zz = v * scale; Cf[idx] = zz; Cb[idx] = f2b(__expf(zz)); }
      }
    }
  }
}

// linv[row] = 1/sum(E[row][:]) over bf16 matrix E [R x C], one 256-thr block per row
__global__ __launch_bounds__(256) void rowsum_att(const unsigned short* __restrict__ E,
                                                  int C, float* __restrict__ linv)
{
  const int row = blockIdx.x, t = threadIdx.x;
  const int lane = t & 63, wid = t >> 6;
  __shared__ float red[4];
  const u16x8* p = (const u16x8*)(E + (size_t)row * C) + t;
  const int nc = C >> 11;              // chunks of 256 threads * 8 elems = 2048
  float s = 0.f;
  for (int c = 0; c < nc; ++c){
    const u16x8 a = p[c * 256];
    #pragma unroll
    for (int j = 0; j < 8; ++j) s += b2f(a[j]);
  }
  #pragma unroll
  for (int o = 32; o; o >>= 1) s += __shfl_xor(s, o, 64);
  if (lane == 0) red[wid] = s;
  __syncthreads();
  if (t == 0) linv[row] = 1.0f / (red[0] + red[1] + red[2] + red[3]);
}

// split-K reduce with row normalization:
// Cf[i] += linv[row]*sum_s P[s][i]; Cb[i] = bf16(Cf[i]); 4 floats/thread
__global__ __launch_bounds__(256) void reduce_splitk(
    const float* __restrict__ P, int S, size_t stride4,
    const float* __restrict__ linv, int d4,
    float* __restrict__ Cf, unsigned short* __restrict__ Cb, int n4)
{
  const int i = blockIdx.x * 256 + threadIdx.x;
  if (i >= n4) return;
  f32x4 s = {0.f, 0.f, 0.f, 0.f};
  for (int k = 0; k < S; ++k) s += ((const f32x4*)P)[(size_t)k * stride4 + i];
  const float li = linv[i / d4];
  f32x4 r = ((const f32x4*)Cf)[i];
  r += s * li;
  ((f32x4*)Cf)[i] = r;
  u16x4 o;
  o[0] = f2b(r[0]); o[1] = f2b(r[1]); o[2] = f2b(r[2]); o[3] = f2b(r[3]);
  ((u16x4*)Cb)[i] = o;
}

// fp32 -> (optional fp32 copy) + bf16, 8 elements/thread
__global__ void cvt8(const float* __restrict__ src, float* __restrict__ dstf,
                     unsigned short* __restrict__ dstb, int n8)
{
  const int i = blockIdx.x * 256 + threadIdx.x;
  if (i >= n8) return;
  const f32x4 a = ((const f32x4*)src)[2*i];
  const f32x4 b = ((const f32x4*)src)[2*i + 1];
  if (dstf){ ((f32x4*)dstf)[2*i] = a; ((f32x4*)dstf)[2*i + 1] = b; }
  u16x8 o;
  o[0]=f2b(a[0]); o[1]=f2b(a[1]); o[2]=f2b(a[2]); o[3]=f2b(a[3]);
  o[4]=f2b(b[0]); o[5]=f2b(b[1]); o[6]=f2b(b[2]); o[7]=f2b(b[3]);
  ((u16x8*)dstb)[i] = o;
}

extern "C" void kernel_launch(void* const* d_in, const int* in_sizes, int n_in,
                              void* d_out, int out_size, void* d_ws, size_t ws_size,
                              hipStream_t stream)
{
  (void)in_sizes; (void)n_in; (void)out_size; (void)ws_size;
  const float* sents = (const float*)d_in[0];
  const float* funcs = (const float*)d_in[1];
  const float* WvA   = (const float*)d_in[2];   // Wv_f2s
  const float* bvA   = (const float*)d_in[3];
  const float* WvB   = (const float*)d_in[4];   // Wv_s2f
  const float* bvB   = (const float*)d_in[5];

  const int NS = 16384, NF = 4096, D = 768;

  float* outS = (float*)d_out;                        // [NS, D]
  float* outF = outS + (size_t)NS * D;                // [NF, D]
  float* outZ = outF + (size_t)NF * D;                // [NS, NF]

  char* ws = (char*)d_ws;
  unsigned short* att = (unsigned short*)ws;  ws += (size_t)NS * NF * 2;   // shared att / z2 buffer
  unsigned short* z2  = att;                                               // disjoint lifetimes
  unsigned short* sb  = (unsigned short*)ws;  ws += (size_t)NS * D * 2;
  unsigned short* fb  = (unsigned short*)ws;  ws += (size_t)NF * D * 2;
  unsigned short* fvT = (unsigned short*)ws;  ws += (size_t)D * NF * 2;
  unsigned short* svT = (unsigned short*)ws;  ws += (size_t)D * NS * 2;
  unsigned short* wA  = (unsigned short*)ws;  ws += (size_t)D * D * 2;
  unsigned short* wB  = (unsigned short*)ws;  ws += (size_t)D * D * 2;
  float* linv = (float*)ws;  ws += (size_t)NS * 4;          // 64KB inverse row sums
  float* Pbuf = (float*)ws;  ws += (size_t)NS * D * 2 * 4;  // 100.7MB split-K partials
                                                            // (16384*768*2 == 4096*768*8)

  const float scale = 0.036084391824351615f;  // 1/sqrt(768)

  cvt8<<<dim3((NS*D/8 + 255)/256), 256, 0, stream>>>(sents, outS, sb, NS*D/8);
  cvt8<<<dim3((NF*D/8 + 255)/256), 256, 0, stream>>>(funcs, outF, fb, NF*D/8);
  cvt8<<<dim3((D*D/8 + 255)/256),  256, 0, stream>>>(WvA, nullptr, wA, D*D/8);
  cvt8<<<dim3((D*D/8 + 255)/256),  256, 0, stream>>>(WvB, nullptr, wB, D*D/8);

  for (int it = 0; it < 4; ++it){
    // fvT[d][f] = sum_k Wv_f2s[d][k]*func_hid[f][k] + bv_f2s[d]   (= func_val^T)
    gemm_bt<2><<<dim3(NF/128, D/128, 1), dim3(256), 0, stream>>>(wA, fb, D, NF, D, 0.f, bvA, nullptr, fvT);
    if (it < 3){
      // att = exp(scale * sents_hid @ func_hid^T)  (bf16, unnormalized)
      gemm_bt<5><<<dim3(NF/128, NS/128, 1), dim3(256), 0, stream>>>(sb, fb, NS, NF, D, scale, nullptr, nullptr, att);
    } else {
      // + z fp32 (returned)
      gemm_bt<6><<<dim3(NF/128, NS/128, 1), dim3(256), 0, stream>>>(sb, fb, NS, NF, D, scale, nullptr, outZ, att);
    }
    rowsum_att<<<dim3(NS), 256, 0, stream>>>(att, NF, linv);
    // sents_hid += linv * (att_un @ func_val) : split-K S=2, then normalize-reduce
    gemm_bt<4><<<dim3(D/128, NS/128, 2), dim3(256), 0, stream>>>(att, fvT, NS, D, 2048, 0.f, nullptr, Pbuf, nullptr);
    reduce_splitk<<<dim3(NS*D/4/256), 256, 0, stream>>>(Pbuf, 2, (size_t)NS*D/4, linv, D/4, outS, sb, NS*D/4);
    // svT[d][s] = sum_k Wv_s2f[d][k]*sents_hid[s][k] + bv_s2f[d]  (= sent_val^T)
    gemm_bt<2><<<dim3(NS/128, D/128, 1), dim3(256), 0, stream>>>(wB, sb, D, NS, D, 0.f, bvB, nullptr, svT);
    // z2_un = exp(scale * func_hid @ sents_hid^T)  (bf16)
    gemm_bt<5><<<dim3(NS/128, NF/128, 1), dim3(256), 0, stream>>>(fb, sb, NF, NS, D, scale, nullptr, nullptr, z2);
    rowsum_att<<<dim3(NF), 256, 0, stream>>>(z2, NS, linv);
    // func_hid += linv * (z2_un @ sent_val) : split-K S=8, then normalize-reduce
    gemm_bt<4><<<dim3(D/128, NF/128, 8), dim3(256), 0, stream>>>(z2, svT, NF, D, 2048, 0.f, nullptr, Pbuf, nullptr);
    reduce_splitk<<<dim3(NF*D/4/256), 256, 0, stream>>>(Pbuf, 8, (size_t)NF*D/4, linv, D/4, outF, fb, NF*D/4);
  }
}

// Round 7
// 2424.565 us; speedup vs baseline: 1.2215x; 1.0643x over previous
//
#include <hip/hip_runtime.h>
#include <stdint.h>

typedef __attribute__((ext_vector_type(8))) short s16x8;
typedef __attribute__((ext_vector_type(8))) unsigned short u16x8;
typedef __attribute__((ext_vector_type(4))) unsigned short u16x4;
typedef __attribute__((ext_vector_type(4))) float f32x4;

__device__ inline unsigned short f2b(float f){
  unsigned u = __builtin_bit_cast(unsigned, f);
  u = u + 0x7fffu + ((u >> 16) & 1u);
  return (unsigned short)(u >> 16);
}
__device__ inline float b2f(unsigned short h){
  unsigned u = ((unsigned)h) << 16;
  return __builtin_bit_cast(float, u);
}

typedef __attribute__((address_space(1))) const unsigned g_uint;
typedef __attribute__((address_space(3))) unsigned l_uint;

__device__ inline void gload_lds16(const void* g, void* l){
  __builtin_amdgcn_global_load_lds((g_uint*)reinterpret_cast<uintptr_t>(g),
                                   (l_uint*)reinterpret_cast<uintptr_t>(l), 16, 0, 0);
}

// C[m][n] = sum_k A[m][k] * B[n][k]   (A: [M,K], B: [N,K], both row-major bf16)
// K range per block: [bz*KS, bz*KS+KS);  leading dim = gridDim.z * KS
// EPI 2: Cb[idx] = bf16(v + bias[row])
// EPI 4: Cf[bz*M*N + idx] = v                    (split-K partial)
// EPI 5: Cb[idx] = bf16(exp(v*scale))            (unnormalized softmax numerator)
// EPI 6: EPI 5 + Cf[idx] = v*scale               (last-iter z output)
// EPI 7: o = Cf[idx] + linv[row]*v; Cf[idx]=o; Cb[idx]=bf16(o)  (direct attention update)
template<int EPI>
__global__ __launch_bounds__(256, 4) void gemm_bt(
    const unsigned short* __restrict__ A, const unsigned short* __restrict__ B,
    int M, int N, int KS, float scale, const float* __restrict__ bias,
    const float* __restrict__ linv,
    float* __restrict__ Cf, unsigned short* __restrict__ Cb)
{
  __shared__ unsigned short As[128*64];
  __shared__ unsigned short Bs[128*64];
  const int tid  = threadIdx.x;
  const int wid  = tid >> 6, lane = tid & 63;
  const int wr   = wid >> 1, wc = wid & 1;

  // ---- bijective XCD-aware swizzle (all launch grids have total % 8 == 0) ----
  const unsigned gx = gridDim.x, gy = gridDim.y;
  const unsigned lin = blockIdx.x + gx*(blockIdx.y + gy*blockIdx.z);
  const unsigned q   = (gx*gy*gridDim.z) >> 3;
  const unsigned w   = (lin & 7)*q + (lin >> 3);
  const unsigned bxs = w % gx;
  const unsigned rest = w / gx;
  const unsigned bys = rest % gy;
  const unsigned bzs = rest / gy;

  const int bm   = bys * 128, bn = bxs * 128;
  const int kb   = bzs * KS, ke = kb + KS;

  f32x4 acc[4][4] = {};

  // ---- staging geometry (global source pre-swizzled; LDS written linearly) ----
  const int l8   = lane >> 3;
  const int scol = ((((lane & 7) << 4) ^ (l8 << 4)) >> 1);
  const int Klead = gridDim.z * KS;

  const unsigned short* Ag[4]; const unsigned short* Bg[4];
  unsigned short* Al[4]; unsigned short* Bl[4];
  #pragma unroll
  for (int i = 0; i < 4; ++i){
    const int row = wid*32 + i*8 + l8;
    Ag[i] = A + (size_t)(bm + row) * Klead + scol;
    Bg[i] = B + (size_t)(bn + row) * Klead + scol;
    Al[i] = As + (wid*4 + i) * 512;
    Bl[i] = Bs + (wid*4 + i) * 512;
  }

  // ---- fragment read geometry ----
  const int fr    = lane & 15;
  const int fk    = (lane >> 4) << 4;
  const int amask = (fr & 7) << 4;

  for (int k0 = kb; k0 < ke; k0 += 64){
    if (k0 != kb) __syncthreads();
    #pragma unroll
    for (int i = 0; i < 4; ++i){
      gload_lds16(Ag[i] + k0, Al[i]);
      gload_lds16(Bg[i] + k0, Bl[i]);
    }
    __syncthreads();
    #pragma unroll
    for (int kk = 0; kk < 2; ++kk){
      s16x8 af[4], bf[4];
      #pragma unroll
      for (int m = 0; m < 4; ++m){
        const int row = (wr << 6) + m*16 + fr;
        const int off = row*128 + (((kk << 6) + fk) ^ amask);
        af[m] = *(const s16x8*)((const char*)As + off);
      }
      #pragma unroll
      for (int n = 0; n < 4; ++n){
        const int row = (wc << 6) + n*16 + fr;
        const int off = row*128 + (((kk << 6) + fk) ^ amask);
        bf[n] = *(const s16x8*)((const char*)Bs + off);
      }
      #pragma unroll
      for (int m = 0; m < 4; ++m)
        #pragma unroll
        for (int n = 0; n < 4; ++n)
          acc[m][n] = __builtin_amdgcn_mfma_f32_16x16x32_bf16(af[m], bf[n], acc[m][n], 0, 0, 0);
    }
  }

  // ---- epilogue ----
  const int gr0 = bm + (wr << 6) + ((lane >> 4) << 2);
  const int gc0 = bn + (wc << 6) + (lane & 15);
  const size_t pbase = (size_t)bzs * M * N;
  #pragma unroll
  for (int m = 0; m < 4; ++m){
    #pragma unroll
    for (int j = 0; j < 4; ++j){
      const int row = gr0 + m*16 + j;
      const float li = (EPI == 7) ? linv[row] : 0.f;
      #pragma unroll
      for (int n = 0; n < 4; ++n){
        const int col = gc0 + n*16;
        const size_t idx = (size_t)row * N + col;
        const float v = acc[m][n][j];
        if      (EPI == 2) Cb[idx] = f2b(v + bias[row]);
        else if (EPI == 4) Cf[pbase + idx] = v;
        else if (EPI == 5) Cb[idx] = f2b(__expf(v * scale));
        else if (EPI == 6){ const float zz = v * scale; Cf[idx] = zz; Cb[idx] = f2b(__expf(zz)); }
        else if (EPI == 7){ const float o = Cf[idx] + li * v; Cf[idx] = o; Cb[idx] = f2b(o); }
      }
    }
  }
}

// linv[row] = 1/sum(E[row][:]) over bf16 matrix E [R x C], one 256-thr block per row
__global__ __launch_bounds__(256) void rowsum_att(const unsigned short* __restrict__ E,
                                                  int C, float* __restrict__ linv)
{
  const int row = blockIdx.x, t = threadIdx.x;
  const int lane = t & 63, wid = t >> 6;
  __shared__ float red[4];
  const u16x8* p = (const u16x8*)(E + (size_t)row * C) + t;
  const int nc = C >> 11;              // chunks of 256 threads * 8 elems = 2048
  float s = 0.f;
  for (int c = 0; c < nc; ++c){
    const u16x8 a = p[c * 256];
    #pragma unroll
    for (int j = 0; j < 8; ++j) s += b2f(a[j]);
  }
  #pragma unroll
  for (int o = 32; o; o >>= 1) s += __shfl_xor(s, o, 64);
  if (lane == 0) red[wid] = s;
  __syncthreads();
  if (t == 0) linv[row] = 1.0f / (red[0] + red[1] + red[2] + red[3]);
}

// split-K reduce with row normalization:
// Cf[i] += linv[row]*sum_s P[s][i]; Cb[i] = bf16(Cf[i]); 4 floats/thread
__global__ __launch_bounds__(256) void reduce_splitk(
    const float* __restrict__ P, int S, size_t stride4,
    const float* __restrict__ linv, int d4,
    float* __restrict__ Cf, unsigned short* __restrict__ Cb, int n4)
{
  const int i = blockIdx.x * 256 + threadIdx.x;
  if (i >= n4) return;
  f32x4 s = {0.f, 0.f, 0.f, 0.f};
  for (int k = 0; k < S; ++k) s += ((const f32x4*)P)[(size_t)k * stride4 + i];
  const float li = linv[i / d4];
  f32x4 r = ((const f32x4*)Cf)[i];
  r += s * li;
  ((f32x4*)Cf)[i] = r;
  u16x4 o;
  o[0] = f2b(r[0]); o[1] = f2b(r[1]); o[2] = f2b(r[2]); o[3] = f2b(r[3]);
  ((u16x4*)Cb)[i] = o;
}

// fp32 -> (optional fp32 copy) + bf16, 8 elements/thread
__global__ void cvt8(const float* __restrict__ src, float* __restrict__ dstf,
                     unsigned short* __restrict__ dstb, int n8)
{
  const int i = blockIdx.x * 256 + threadIdx.x;
  if (i >= n8) return;
  const f32x4 a = ((const f32x4*)src)[2*i];
  const f32x4 b = ((const f32x4*)src)[2*i + 1];
  if (dstf){ ((f32x4*)dstf)[2*i] = a; ((f32x4*)dstf)[2*i + 1] = b; }
  u16x8 o;
  o[0]=f2b(a[0]); o[1]=f2b(a[1]); o[2]=f2b(a[2]); o[3]=f2b(a[3]);
  o[4]=f2b(b[0]); o[5]=f2b(b[1]); o[6]=f2b(b[2]); o[7]=f2b(b[3]);
  ((u16x8*)dstb)[i] = o;
}

extern "C" void kernel_launch(void* const* d_in, const int* in_sizes, int n_in,
                              void* d_out, int out_size, void* d_ws, size_t ws_size,
                              hipStream_t stream)
{
  (void)in_sizes; (void)n_in; (void)out_size; (void)ws_size;
  const float* sents = (const float*)d_in[0];
  const float* funcs = (const float*)d_in[1];
  const float* WvA   = (const float*)d_in[2];   // Wv_f2s
  const float* bvA   = (const float*)d_in[3];
  const float* WvB   = (const float*)d_in[4];   // Wv_s2f
  const float* bvB   = (const float*)d_in[5];

  const int NS = 16384, NF = 4096, D = 768;

  float* outS = (float*)d_out;                        // [NS, D]
  float* outF = outS + (size_t)NS * D;                // [NF, D]
  float* outZ = outF + (size_t)NF * D;                // [NS, NF]

  char* ws = (char*)d_ws;
  unsigned short* att = (unsigned short*)ws;  ws += (size_t)NS * NF * 2;   // shared att / z2 buffer
  unsigned short* z2  = att;                                               // disjoint lifetimes
  unsigned short* sb  = (unsigned short*)ws;  ws += (size_t)NS * D * 2;
  unsigned short* fb  = (unsigned short*)ws;  ws += (size_t)NF * D * 2;
  unsigned short* fvT = (unsigned short*)ws;  ws += (size_t)D * NF * 2;
  unsigned short* svT = (unsigned short*)ws;  ws += (size_t)D * NS * 2;
  unsigned short* wA  = (unsigned short*)ws;  ws += (size_t)D * D * 2;
  unsigned short* wB  = (unsigned short*)ws;  ws += (size_t)D * D * 2;
  float* linv = (float*)ws;  ws += (size_t)NS * 4;          // 64KB inverse row sums
  float* Pbuf = (float*)ws;  ws += (size_t)NF * D * 4 * 4;  // 50.3MB split-K partials (fupd S=4)

  const float scale = 0.036084391824351615f;  // 1/sqrt(768)

  cvt8<<<dim3((NS*D/8 + 255)/256), 256, 0, stream>>>(sents, outS, sb, NS*D/8);
  cvt8<<<dim3((NF*D/8 + 255)/256), 256, 0, stream>>>(funcs, outF, fb, NF*D/8);
  cvt8<<<dim3((D*D/8 + 255)/256),  256, 0, stream>>>(WvA, nullptr, wA, D*D/8);
  cvt8<<<dim3((D*D/8 + 255)/256),  256, 0, stream>>>(WvB, nullptr, wB, D*D/8);

  for (int it = 0; it < 4; ++it){
    // fvT[d][f] = sum_k Wv_f2s[d][k]*func_hid[f][k] + bv_f2s[d]   (= func_val^T)
    gemm_bt<2><<<dim3(NF/128, D/128, 1), dim3(256), 0, stream>>>(wA, fb, D, NF, D, 0.f, bvA, nullptr, nullptr, fvT);
    if (it < 3){
      // att = exp(scale * sents_hid @ func_hid^T)  (bf16, unnormalized)
      gemm_bt<5><<<dim3(NF/128, NS/128, 1), dim3(256), 0, stream>>>(sb, fb, NS, NF, D, scale, nullptr, nullptr, nullptr, att);
    } else {
      // + z fp32 (returned)
      gemm_bt<6><<<dim3(NF/128, NS/128, 1), dim3(256), 0, stream>>>(sb, fb, NS, NF, D, scale, nullptr, nullptr, outZ, att);
    }
    rowsum_att<<<dim3(NS), 256, 0, stream>>>(att, NF, linv);
    // sents_hid += linv * (att_un @ func_val)  — direct epilogue update (768 blocks, no split)
    gemm_bt<7><<<dim3(D/128, NS/128, 1), dim3(256), 0, stream>>>(att, fvT, NS, D, NF, 0.f, nullptr, linv, outS, sb);
    // svT[d][s] = sum_k Wv_s2f[d][k]*sents_hid[s][k] + bv_s2f[d]  (= sent_val^T)
    gemm_bt<2><<<dim3(NS/128, D/128, 1), dim3(256), 0, stream>>>(wB, sb, D, NS, D, 0.f, bvB, nullptr, nullptr, svT);
    // z2_un = exp(scale * func_hid @ sents_hid^T)  (bf16)
    gemm_bt<5><<<dim3(NS/128, NF/128, 1), dim3(256), 0, stream>>>(fb, sb, NF, NS, D, scale, nullptr, nullptr, nullptr, z2);
    rowsum_att<<<dim3(NF), 256, 0, stream>>>(z2, NS, linv);
    // func_hid += linv * (z2_un @ sent_val) : split-K S=4 (K=16384 -> 4096/chunk), then reduce
    gemm_bt<4><<<dim3(D/128, NF/128, 4), dim3(256), 0, stream>>>(z2, svT, NF, D, 4096, 0.f, nullptr, nullptr, Pbuf, nullptr);
    reduce_splitk<<<dim3(NF*D/4/256), 256, 0, stream>>>(Pbuf, 4, (size_t)NF*D/4, linv, D/4, outF, fb, NF*D/4);
  }
}

// Round 8
// 2268.828 us; speedup vs baseline: 1.3053x; 1.0686x over previous
//
#include <hip/hip_runtime.h>
#include <stdint.h>

typedef __attribute__((ext_vector_type(8))) short s16x8;
typedef __attribute__((ext_vector_type(8))) unsigned short u16x8;
typedef __attribute__((ext_vector_type(4))) unsigned short u16x4;
typedef __attribute__((ext_vector_type(4))) float f32x4;

__device__ inline unsigned short f2b(float f){
  unsigned u = __builtin_bit_cast(unsigned, f);
  u = u + 0x7fffu + ((u >> 16) & 1u);
  return (unsigned short)(u >> 16);
}
__device__ inline float b2f(unsigned short h){
  unsigned u = ((unsigned)h) << 16;
  return __builtin_bit_cast(float, u);
}

typedef __attribute__((address_space(1))) const unsigned g_uint;
typedef __attribute__((address_space(3))) unsigned l_uint;

__device__ inline void gload_lds16(const void* g, void* l){
  __builtin_amdgcn_global_load_lds((g_uint*)reinterpret_cast<uintptr_t>(g),
                                   (l_uint*)reinterpret_cast<uintptr_t>(l), 16, 0, 0);
}

#define BARF() { __builtin_amdgcn_s_barrier(); asm volatile("" ::: "memory"); }

// ============================================================================
// 256x256 8-phase GEMM (T2+T3+T4+T5), C = A·B^T, K multiple of 128.
// A:[M,K] B:[N,K] bf16 row-major. 512 threads = 8 waves (2M x 4N).
// LDS: 2 slots x 64KB. Slot: alpha(A m0-rows)[128][64]@0, beta(A m1)@16K,
//      gamma(B kslab0)[256][32]@32K, delta(B kslab1)@48K.
// EPI 5: Cb = bf16(exp(v*scale));  EPI 6: EPI5 + Cf = v*scale
// ============================================================================
template<int EPI>
__global__ __launch_bounds__(512, 2) void gemm256(
    const unsigned short* __restrict__ A, const unsigned short* __restrict__ B,
    int M, int N, int K, float scale,
    float* __restrict__ Cf, unsigned short* __restrict__ Cb)
{
  __shared__ __align__(16) char ldsraw[131072];
  const int tid  = threadIdx.x;
  const int wid  = tid >> 6, lane = tid & 63;
  const int wm   = wid >> 2, wn = wid & 3;

  // bijective XCD swizzle (grid total % 8 == 0)
  const unsigned gx = gridDim.x, gy = gridDim.y;
  const unsigned lin = blockIdx.x + gx*blockIdx.y;
  const unsigned q   = (gx*gy) >> 3;
  const unsigned w   = (lin & 7)*q + (lin >> 3);
  const int bm = (w / gx) * 256, bn = (w % gx) * 256;

  const int NT = K >> 6;

  f32x4 acc[8][4] = {};

  // ---- staging (pre-swizzled global source, linear LDS dest) ----
  auto stageA = [&](int T, int halfm){            // halfm: 0=alpha(m0), 1=beta(m1)
    const int kb = T << 6;
    char* ldsb = ldsraw + ((T & 1) << 16) + halfm*16384;
    #pragma unroll
    for (int i = 0; i < 2; ++i){
      const int lr  = i*64 + (tid >> 3);          // LDS row 0..127
      const int gtr = halfm*64 + ((lr < 64) ? lr : lr + 64);
      const int sc  = ((tid & 7)*8) ^ ((lr & 7)*8);
      gload_lds16(A + (size_t)(bm + gtr)*K + kb + sc, ldsb + i*8192 + tid*16);
    }
  };
  auto stageB = [&](int T, int halfk){            // halfk: 0=gamma(k0), 1=delta(k1)
    const int kb = (T << 6) + halfk*32;
    char* ldsb = ldsraw + ((T & 1) << 16) + 32768 + halfk*16384;
    #pragma unroll
    for (int i = 0; i < 2; ++i){
      const int lr = i*128 + (tid >> 2);          // LDS row 0..255
      const int sc = ((tid & 3)*8) ^ ((lr & 3)*8);
      gload_lds16(B + (size_t)(bn + lr)*K + kb + sc, ldsb + i*8192 + tid*16);
    }
  };

  // ---- fragment reads (swizzled) ----
  const int fr = lane & 15;
  const int fo = (lane >> 4) << 4;      // k-offset bytes within slab
  const int amask = (fr & 7) << 4;
  const int bmask = (fr & 3) << 4;

  auto rdA = [&](const char* ldsS, int mh, int kk, s16x8* af){
    const char* ab = ldsS + mh*16384;
    #pragma unroll
    for (int mf = 0; mf < 4; ++mf){
      const int r = wm*64 + mf*16 + fr;
      af[mf] = *(const s16x8*)(ab + r*128 + ((kk*64 + fo) ^ amask));
    }
  };
  auto rdB = [&](const char* ldsS, int kk, s16x8* bf){
    const char* bb = ldsS + 32768 + kk*16384;
    #pragma unroll
    for (int nf = 0; nf < 4; ++nf){
      const int r = wn*64 + nf*16 + fr;
      bf[nf] = *(const s16x8*)(bb + r*64 + (fo ^ bmask));
    }
  };

  // ---- prologue: gamma0,alpha0,beta0,delta0,gamma1,alpha1 ; vmcnt(4) ----
  stageB(0, 0); stageA(0, 0); stageA(0, 1); stageB(0, 1);
  stageB(1, 0); stageA(1, 0);
  asm volatile("s_waitcnt vmcnt(4)" ::: "memory");
  BARF();

  // ---- main loop: 4 phases per K-tile ----
  for (int T = 0; T < NT; ++T){
    const char* ldsS = ldsraw + ((T & 1) << 16);
    s16x8 af[4], bf[4];
    // g0: m0 x k0 ; stage beta(T+1)
    rdA(ldsS, 0, 0, af); rdB(ldsS, 0, bf);
    if (T + 1 < NT) stageA(T + 1, 1);
    BARF();
    __builtin_amdgcn_s_setprio(1);
    #pragma unroll
    for (int mf = 0; mf < 4; ++mf)
      #pragma unroll
      for (int nf = 0; nf < 4; ++nf)
        acc[mf][nf] = __builtin_amdgcn_mfma_f32_16x16x32_bf16(af[mf], bf[nf], acc[mf][nf], 0, 0, 0);
    __builtin_amdgcn_s_setprio(0);
    BARF();
    // g1: m1 x k0 ; stage delta(T+1)
    rdA(ldsS, 1, 0, af);
    if (T + 1 < NT) stageB(T + 1, 1);
    BARF();
    __builtin_amdgcn_s_setprio(1);
    #pragma unroll
    for (int mf = 0; mf < 4; ++mf)
      #pragma unroll
      for (int nf = 0; nf < 4; ++nf)
        acc[4 + mf][nf] = __builtin_amdgcn_mfma_f32_16x16x32_bf16(af[mf], bf[nf], acc[4 + mf][nf], 0, 0, 0);
    __builtin_amdgcn_s_setprio(0);
    BARF();
    // g2: m0 x k1 ; stage gamma(T+2)
    rdA(ldsS, 0, 1, af); rdB(ldsS, 1, bf);
    if (T + 2 < NT) stageB(T + 2, 0);
    BARF();
    __builtin_amdgcn_s_setprio(1);
    #pragma unroll
    for (int mf = 0; mf < 4; ++mf)
      #pragma unroll
      for (int nf = 0; nf < 4; ++nf)
        acc[mf][nf] = __builtin_amdgcn_mfma_f32_16x16x32_bf16(af[mf], bf[nf], acc[mf][nf], 0, 0, 0);
    __builtin_amdgcn_s_setprio(0);
    BARF();
    // g3: m1 x k1 ; stage alpha(T+2) ; counted vmcnt
    rdA(ldsS, 1, 1, af);
    if (T + 2 < NT) stageA(T + 2, 0);
    BARF();
    __builtin_amdgcn_s_setprio(1);
    #pragma unroll
    for (int mf = 0; mf < 4; ++mf)
      #pragma unroll
      for (int nf = 0; nf < 4; ++nf)
        acc[4 + mf][nf] = __builtin_amdgcn_mfma_f32_16x16x32_bf16(af[mf], bf[nf], acc[4 + mf][nf], 0, 0, 0);
    __builtin_amdgcn_s_setprio(0);
    if (T < NT - 2) { asm volatile("s_waitcnt vmcnt(4)" ::: "memory"); }
    else           { asm volatile("s_waitcnt vmcnt(0)" ::: "memory"); }
    BARF();
  }

  // ---- epilogue ----
  const int er0 = bm + wm*128 + ((lane >> 4) << 2);
  const int ec0 = bn + wn*64  + (lane & 15);
  #pragma unroll
  for (int mf = 0; mf < 8; ++mf){
    #pragma unroll
    for (int nf = 0; nf < 4; ++nf){
      #pragma unroll
      for (int j = 0; j < 4; ++j){
        const int row = er0 + mf*16 + j;
        const int col = ec0 + nf*16;
        const size_t idx = (size_t)row * N + col;
        const float v = acc[mf][nf][j];
        if (EPI == 5) Cb[idx] = f2b(__expf(v * scale));
        else { const float zz = v * scale; Cf[idx] = zz; Cb[idx] = f2b(__expf(zz)); }
      }
    }
  }
}

// ============================================================================
// 128x128 2-phase GEMM (proven) for projections and updates
// EPI 2: Cb = bf16(v + bias[row])
// EPI 4: Cf[bz*M*N + idx] = v                    (split-K partial)
// EPI 7: o = Cf[idx] + linv[row]*v; Cf=o; Cb=bf16(o)
// ============================================================================
template<int EPI>
__global__ __launch_bounds__(256, 4) void gemm_bt(
    const unsigned short* __restrict__ A, const unsigned short* __restrict__ B,
    int M, int N, int KS, float scale, const float* __restrict__ bias,
    const float* __restrict__ linv,
    float* __restrict__ Cf, unsigned short* __restrict__ Cb)
{
  __shared__ unsigned short As[128*64];
  __shared__ unsigned short Bs[128*64];
  const int tid  = threadIdx.x;
  const int wid  = tid >> 6, lane = tid & 63;
  const int wr   = wid >> 1, wc = wid & 1;

  const unsigned gx = gridDim.x, gy = gridDim.y;
  const unsigned lin = blockIdx.x + gx*(blockIdx.y + gy*blockIdx.z);
  const unsigned q   = (gx*gy*gridDim.z) >> 3;
  const unsigned w   = (lin & 7)*q + (lin >> 3);
  const unsigned bxs = w % gx;
  const unsigned rest = w / gx;
  const unsigned bys = rest % gy;
  const unsigned bzs = rest / gy;

  const int bm   = bys * 128, bn = bxs * 128;
  const int kb   = bzs * KS, ke = kb + KS;

  f32x4 acc[4][4] = {};

  const int l8   = lane >> 3;
  const int scol = ((((lane & 7) << 4) ^ (l8 << 4)) >> 1);
  const int Klead = gridDim.z * KS;

  const unsigned short* Ag[4]; const unsigned short* Bg[4];
  unsigned short* Al[4]; unsigned short* Bl[4];
  #pragma unroll
  for (int i = 0; i < 4; ++i){
    const int row = wid*32 + i*8 + l8;
    Ag[i] = A + (size_t)(bm + row) * Klead + scol;
    Bg[i] = B + (size_t)(bn + row) * Klead + scol;
    Al[i] = As + (wid*4 + i) * 512;
    Bl[i] = Bs + (wid*4 + i) * 512;
  }

  const int fr    = lane & 15;
  const int fk    = (lane >> 4) << 4;
  const int amask = (fr & 7) << 4;

  for (int k0 = kb; k0 < ke; k0 += 64){
    if (k0 != kb) __syncthreads();
    #pragma unroll
    for (int i = 0; i < 4; ++i){
      gload_lds16(Ag[i] + k0, Al[i]);
      gload_lds16(Bg[i] + k0, Bl[i]);
    }
    __syncthreads();
    #pragma unroll
    for (int kk = 0; kk < 2; ++kk){
      s16x8 af[4], bf[4];
      #pragma unroll
      for (int m = 0; m < 4; ++m){
        const int row = (wr << 6) + m*16 + fr;
        const int off = row*128 + (((kk << 6) + fk) ^ amask);
        af[m] = *(const s16x8*)((const char*)As + off);
      }
      #pragma unroll
      for (int n = 0; n < 4; ++n){
        const int row = (wc << 6) + n*16 + fr;
        const int off = row*128 + (((kk << 6) + fk) ^ amask);
        bf[n] = *(const s16x8*)((const char*)Bs + off);
      }
      #pragma unroll
      for (int m = 0; m < 4; ++m)
        #pragma unroll
        for (int n = 0; n < 4; ++n)
          acc[m][n] = __builtin_amdgcn_mfma_f32_16x16x32_bf16(af[m], bf[n], acc[m][n], 0, 0, 0);
    }
  }

  const int gr0 = bm + (wr << 6) + ((lane >> 4) << 2);
  const int gc0 = bn + (wc << 6) + (lane & 15);
  const size_t pbase = (size_t)bzs * M * N;
  #pragma unroll
  for (int m = 0; m < 4; ++m){
    #pragma unroll
    for (int j = 0; j < 4; ++j){
      const int row = gr0 + m*16 + j;
      const float li = (EPI == 7) ? linv[row] : 0.f;
      #pragma unroll
      for (int n = 0; n < 4; ++n){
        const int col = gc0 + n*16;
        const size_t idx = (size_t)row * N + col;
        const float v = acc[m][n][j];
        if      (EPI == 2) Cb[idx] = f2b(v + bias[row]);
        else if (EPI == 4) Cf[pbase + idx] = v;
        else if (EPI == 7){ const float o = Cf[idx] + li * v; Cf[idx] = o; Cb[idx] = f2b(o); }
      }
    }
  }
}

// linv[row] = 1/sum(E[row][:]) over bf16 matrix E [R x C], one 256-thr block per row
__global__ __launch_bounds__(256) void rowsum_att(const unsigned short* __restrict__ E,
                                                  int C, float* __restrict__ linv)
{
  const int row = blockIdx.x, t = threadIdx.x;
  const int lane = t & 63, wid = t >> 6;
  __shared__ float red[4];
  const u16x8* p = (const u16x8*)(E + (size_t)row * C) + t;
  const int nc = C >> 11;
  float s = 0.f;
  for (int c = 0; c < nc; ++c){
    const u16x8 a = p[c * 256];
    #pragma unroll
    for (int j = 0; j < 8; ++j) s += b2f(a[j]);
  }
  #pragma unroll
  for (int o = 32; o; o >>= 1) s += __shfl_xor(s, o, 64);
  if (lane == 0) red[wid] = s;
  __syncthreads();
  if (t == 0) linv[row] = 1.0f / (red[0] + red[1] + red[2] + red[3]);
}

// split-K reduce with row normalization
__global__ __launch_bounds__(256) void reduce_splitk(
    const float* __restrict__ P, int S, size_t stride4,
    const float* __restrict__ linv, int d4,
    float* __restrict__ Cf, unsigned short* __restrict__ Cb, int n4)
{
  const int i = blockIdx.x * 256 + threadIdx.x;
  if (i >= n4) return;
  f32x4 s = {0.f, 0.f, 0.f, 0.f};
  for (int k = 0; k < S; ++k) s += ((const f32x4*)P)[(size_t)k * stride4 + i];
  const float li = linv[i / d4];
  f32x4 r = ((const f32x4*)Cf)[i];
  r += s * li;
  ((f32x4*)Cf)[i] = r;
  u16x4 o;
  o[0] = f2b(r[0]); o[1] = f2b(r[1]); o[2] = f2b(r[2]); o[3] = f2b(r[3]);
  ((u16x4*)Cb)[i] = o;
}

// fp32 -> (optional fp32 copy) + bf16
__global__ void cvt8(const float* __restrict__ src, float* __restrict__ dstf,
                     unsigned short* __restrict__ dstb, int n8)
{
  const int i = blockIdx.x * 256 + threadIdx.x;
  if (i >= n8) return;
  const f32x4 a = ((const f32x4*)src)[2*i];
  const f32x4 b = ((const f32x4*)src)[2*i + 1];
  if (dstf){ ((f32x4*)dstf)[2*i] = a; ((f32x4*)dstf)[2*i + 1] = b; }
  u16x8 o;
  o[0]=f2b(a[0]); o[1]=f2b(a[1]); o[2]=f2b(a[2]); o[3]=f2b(a[3]);
  o[4]=f2b(b[0]); o[5]=f2b(b[1]); o[6]=f2b(b[2]); o[7]=f2b(b[3]);
  ((u16x8*)dstb)[i] = o;
}

extern "C" void kernel_launch(void* const* d_in, const int* in_sizes, int n_in,
                              void* d_out, int out_size, void* d_ws, size_t ws_size,
                              hipStream_t stream)
{
  (void)in_sizes; (void)n_in; (void)out_size; (void)ws_size;
  const float* sents = (const float*)d_in[0];
  const float* funcs = (const float*)d_in[1];
  const float* WvA   = (const float*)d_in[2];   // Wv_f2s
  const float* bvA   = (const float*)d_in[3];
  const float* WvB   = (const float*)d_in[4];   // Wv_s2f
  const float* bvB   = (const float*)d_in[5];

  const int NS = 16384, NF = 4096, D = 768;

  float* outS = (float*)d_out;                        // [NS, D]
  float* outF = outS + (size_t)NS * D;                // [NF, D]
  float* outZ = outF + (size_t)NF * D;                // [NS, NF]

  char* ws = (char*)d_ws;
  unsigned short* att = (unsigned short*)ws;  ws += (size_t)NS * NF * 2;   // shared att / z2 buffer
  unsigned short* z2  = att;                                               // disjoint lifetimes
  unsigned short* sb  = (unsigned short*)ws;  ws += (size_t)NS * D * 2;
  unsigned short* fb  = (unsigned short*)ws;  ws += (size_t)NF * D * 2;
  unsigned short* fvT = (unsigned short*)ws;  ws += (size_t)D * NF * 2;
  unsigned short* svT = (unsigned short*)ws;  ws += (size_t)D * NS * 2;
  unsigned short* wA  = (unsigned short*)ws;  ws += (size_t)D * D * 2;
  unsigned short* wB  = (unsigned short*)ws;  ws += (size_t)D * D * 2;
  float* linv = (float*)ws;  ws += (size_t)NS * 4;          // 64KB inverse row sums
  float* Pbuf = (float*)ws;  ws += (size_t)NF * D * 4 * 4;  // 50.3MB split-K partials (fupd S=4)

  const float scale = 0.036084391824351615f;  // 1/sqrt(768)

  cvt8<<<dim3((NS*D/8 + 255)/256), 256, 0, stream>>>(sents, outS, sb, NS*D/8);
  cvt8<<<dim3((NF*D/8 + 255)/256), 256, 0, stream>>>(funcs, outF, fb, NF*D/8);
  cvt8<<<dim3((D*D/8 + 255)/256),  256, 0, stream>>>(WvA, nullptr, wA, D*D/8);
  cvt8<<<dim3((D*D/8 + 255)/256),  256, 0, stream>>>(WvB, nullptr, wB, D*D/8);

  for (int it = 0; it < 4; ++it){
    // fvT[d][f] = Wv_f2s @ func_hid^T + bias  (= func_val^T)
    gemm_bt<2><<<dim3(NF/128, D/128, 1), dim3(256), 0, stream>>>(wA, fb, D, NF, D, 0.f, bvA, nullptr, nullptr, fvT);
    if (it < 3){
      // att = exp(scale * sents_hid @ func_hid^T)  (bf16, unnormalized) — 8-phase engine
      gemm256<5><<<dim3(NF/256, NS/256), dim3(512), 0, stream>>>(sb, fb, NS, NF, D, scale, nullptr, att);
    } else {
      gemm256<6><<<dim3(NF/256, NS/256), dim3(512), 0, stream>>>(sb, fb, NS, NF, D, scale, outZ, att);
    }
    rowsum_att<<<dim3(NS), 256, 0, stream>>>(att, NF, linv);
    // sents_hid += linv * (att_un @ func_val)  — direct epilogue update
    gemm_bt<7><<<dim3(D/128, NS/128, 1), dim3(256), 0, stream>>>(att, fvT, NS, D, NF, 0.f, nullptr, linv, outS, sb);
    // svT[d][s] = Wv_s2f @ sents_hid^T + bias  (= sent_val^T)
    gemm_bt<2><<<dim3(NS/128, D/128, 1), dim3(256), 0, stream>>>(wB, sb, D, NS, D, 0.f, bvB, nullptr, nullptr, svT);
    // z2_un = exp(scale * func_hid @ sents_hid^T)  (bf16) — 8-phase engine
    gemm256<5><<<dim3(NS/256, NF/256), dim3(512), 0, stream>>>(fb, sb, NF, NS, D, scale, nullptr, z2);
    rowsum_att<<<dim3(NF), 256, 0, stream>>>(z2, NS, linv);
    // func_hid += linv * (z2_un @ sent_val) : split-K S=4, then reduce
    gemm_bt<4><<<dim3(D/128, NF/128, 4), dim3(256), 0, stream>>>(z2, svT, NF, D, 4096, 0.f, nullptr, nullptr, Pbuf, nullptr);
    reduce_splitk<<<dim3(NF*D/4/256), 256, 0, stream>>>(Pbuf, 4, (size_t)NF*D/4, linv, D/4, outF, fb, NF*D/4);
  }
}